// Round 12
// baseline (198.710 us; speedup 1.0000x reference)
//
#include <hip/hip_runtime.h>

// Gated SPN, reverse scan over W:
//   h(i,t) = a*x + g1*h(i-1,t+1) + g2*h(i,t+1) + g3*h(i+1,t+1), a = 1-g1-g2-g3
//
// r12: 512 threads / 8 waves per block (2 waves/SIMD -> 256-VGPR budget) so
// the entire next-tile prefetch (32 float4 = 128 VGPRs) is HELD in registers
// across the scan -- at 1024 threads the 128-reg cap forced the compiler to
// sink loads to their use (VGPR=60 every round; serial mem-wait/compute).
// Scan: each lane carries a PAIR of adjacent rows (h0,h1); 48 active lanes =
// 96-row cone, 32 owned pairs (64 rows), 8-pair halo each side; 16 steps per
// anchor (corruption moves 1 row/step). DPP exchange: wave_shr(h1) gives
// h(2p-1), wave_shl(h0) gives h(2p+2). Coefficients 2rows x 4fp16 = 16B ->
// one ds_read_b128 per pair-step. WT=32 (128B HBM granule), fp16 tile,
// 2 W-chunks x 128 slices = 256 blocks, non-draining LDS barriers.

#define HH 512
#define WW 512
#define WT 32
#define NT 512             // 8 waves
#define PPITCH 273         // pair pitch in 16B units (272 pairs + 1 pad)
#define NPAIR 272          // 8 halo + 256 real + 8 halo pairs

typedef _Float16 half4_t __attribute__((ext_vector_type(4)));
typedef _Float16 half8_t __attribute__((ext_vector_type(8)));

struct Regs { float4 x[8], g1[8], g2[8], g3[8]; };   // 8 rounds x 64 rows

__device__ __forceinline__ float dpp_prev(float v) {   // lane i <- lane i-1
    return __int_as_float(__builtin_amdgcn_update_dpp(
        0, __float_as_int(v), 0x138, 0xf, 0xf, false)); // wave_shr:1, invalid->0
}
__device__ __forceinline__ float dpp_next(float v) {   // lane i <- lane i+1
    return __int_as_float(__builtin_amdgcn_update_dpp(
        0, __float_as_int(v), 0x130, 0xf, 0xf, false)); // wave_shl:1, invalid->0
}

// LDS-only barrier: drains lgkm (ds_write visibility), leaves vmem in flight.
__device__ __forceinline__ void lds_barrier() {
    asm volatile("s_waitcnt lgkmcnt(0)" ::: "memory");
    __builtin_amdgcn_s_barrier();
    __builtin_amdgcn_sched_barrier(0);
}

__device__ __forceinline__ half4_t norm_pack(float xx, float g1, float g2, float g3) {
    const float sa = fabsf(g1) + fabsf(g2) + fabsf(g3);
    const float sc = (sa >= 1.0f) ? (1.0f / sa) : 1.0f;
    const float n1 = g1 * sc, n2 = g2 * sc, n3 = g3 * sc;
    const float a  = 1.0f - n1 - n2 - n3;
    half4_t v;
    v.x = (_Float16)(a * xx);
    v.y = (_Float16)n1;
    v.z = (_Float16)n2;
    v.w = (_Float16)n3;
    return v;
}

__global__ __launch_bounds__(NT, 2) void spn_kernel(
    const float* __restrict__ X, const float* __restrict__ G1,
    const float* __restrict__ G2, const float* __restrict__ G3,
    float* __restrict__ OUT)
{
    extern __shared__ char smem[];
    half8_t* tile  = (half8_t*)smem;          // [32 w][PPITCH pairs], 16B/pair
    half4_t* tile4 = (half4_t*)smem;          // same memory, 8B granularity
    float2*  hl0   = (float2*)(smem + (size_t)32 * PPITCH * 16);
    float2*  hl1   = hl0 + NPAIR;

    const int tid   = threadIdx.x;
    const int wv    = tid >> 6;
    const int L     = tid & 63;
    const int pslot = 32 * wv + L;            // pair slot, valid for L<48
    const bool act   = (L < 48);
    const bool owned = (L >= 8) && (L < 40);
    const int r0g   = 2 * (pslot - 8);        // global row of pair's even row
    const int lrow  = tid >> 3;               // staging row base (0..63)
    const int lq    = tid & 7;                // 16B eighth of 128B row segment

    const int slice  = blockIdx.x >> 1;
    const int ch     = blockIdx.x & 1;
    const int cend   = ch ? WW : 288;         // scan region right edge
    const int ntiles = ch ? 8 : 9;
    const int warm   = ch ? 0 : 1;            // ch0's first tile = warmup

    const size_t base = (size_t)slice * (size_t)(HH * WW);
    const float* Xp  = X  + base;
    const float* G1p = G1 + base;
    const float* G2p = G2 + base;
    const float* G3p = G3 + base;
    float* Op = OUT + base;

    // zero-init: halo pair slots (pairs outside [0,256) global) for all 32 w,
    // and both h-lines. Covered by the first lds_barrier.
    {
        const int w = tid >> 4, k = tid & 15;
        const int ps = (k < 8) ? k : (256 + k);   // 0..7 and 264..271
        half8_t z;
        #pragma unroll
        for (int i = 0; i < 8; ++i) z[i] = (_Float16)0.0f;
        tile[w * PPITCH + ps] = z;
    }
    if (tid < NPAIR) {
        hl0[tid] = make_float2(0.0f, 0.0f);
        hl1[tid] = make_float2(0.0f, 0.0f);
    }

    Regs R;
    {   // prologue: load tile 0 (rightmost)
        #pragma unroll
        for (int j = 0; j < 8; ++j) {
            const size_t off = (size_t)(lrow + 64 * j) * WW
                             + (size_t)(cend - WT + 4 * lq);
            R.x[j]  = *(const float4*)(Xp  + off);
            R.g1[j] = *(const float4*)(G1p + off);
            R.g2[j] = *(const float4*)(G2p + off);
            R.g3[j] = *(const float4*)(G3p + off);
        }
    }

    for (int t = 0; t < ntiles; ++t) {
        const int w0 = cend - WT * (t + 1);
        const bool emit = (t >= warm);

        // ---- stage tile t: 8 rounds x 4 cols, fp16 pair-packed ----
        #pragma unroll
        for (int j = 0; j < 8; ++j) {
            const int row  = lrow + 64 * j;
            const int prow = (row >> 1) + 8;          // pair slot
            const int half = row & 1;
            const int bi   = ((4 * lq) * PPITCH + prow) * 2 + half;  // 8B units
            tile4[bi + 0 * 2 * PPITCH] = norm_pack(R.x[j].x, R.g1[j].x, R.g2[j].x, R.g3[j].x);
            tile4[bi + 1 * 2 * PPITCH] = norm_pack(R.x[j].y, R.g1[j].y, R.g2[j].y, R.g3[j].y);
            tile4[bi + 2 * 2 * PPITCH] = norm_pack(R.x[j].z, R.g1[j].z, R.g2[j].z, R.g3[j].z);
            tile4[bi + 3 * 2 * PPITCH] = norm_pack(R.x[j].w, R.g1[j].w, R.g2[j].w, R.g3[j].w);
        }
        lds_barrier();   // tile visible; vmem NOT drained

        // ---- issue next tile's 32 loads; held in regs across the scan ----
        if (t + 1 < ntiles) {
            const int wn = w0 - WT;
            #pragma unroll
            for (int j = 0; j < 8; ++j) {
                const size_t off = (size_t)(lrow + 64 * j) * WW + (size_t)(wn + 4 * lq);
                R.x[j]  = *(const float4*)(Xp  + off);
                R.g1[j] = *(const float4*)(G1p + off);
                R.g2[j] = *(const float4*)(G2p + off);
                R.g3[j] = *(const float4*)(G3p + off);
            }
        }

        float hv0[16], hv1[16];

        // ---- half A: 16 barrier-free pair-steps, cols w0+31 .. w0+16 ----
        {
            float2 hh = act ? hl0[pslot] : make_float2(0.0f, 0.0f);
            float h0 = hh.x, h1 = hh.y;
            if (act) {
                #pragma unroll
                for (int s = 0; s < 16; ++s) {
                    const int q = 31 - s;
                    const half8_t v = tile[q * PPITCH + pslot];
                    const float hu = dpp_prev(h1);     // h(2p-1)
                    const float hd = dpp_next(h0);     // h(2p+2)
                    const float n0 = fmaf((float)v[1], hu,
                                     fmaf((float)v[2], h0,
                                     fmaf((float)v[3], h1, (float)v[0])));
                    const float n1 = fmaf((float)v[5], h0,
                                     fmaf((float)v[6], h1,
                                     fmaf((float)v[7], hd, (float)v[4])));
                    h0 = n0; h1 = n1;
                    hv0[q - 16] = h0; hv1[q - 16] = h1;
                }
                if (owned) hl1[pslot] = make_float2(h0, h1);
            }
        }
        if (owned && emit) {   // store half A: 2 rows x 64B contiguous
            float* b0 = Op + (size_t)r0g * WW + (size_t)(w0 + 16);
            #pragma unroll
            for (int j = 0; j < 4; ++j) {
                *(float4*)(b0 + 4 * j)      = make_float4(hv0[4*j], hv0[4*j+1], hv0[4*j+2], hv0[4*j+3]);
                *(float4*)(b0 + WW + 4 * j) = make_float4(hv1[4*j], hv1[4*j+1], hv1[4*j+2], hv1[4*j+3]);
            }
        }
        lds_barrier();   // hl1 visible

        // ---- half B: 16 barrier-free pair-steps, cols w0+15 .. w0 ----
        {
            float2 hh = act ? hl1[pslot] : make_float2(0.0f, 0.0f);
            float h0 = hh.x, h1 = hh.y;
            if (act) {
                #pragma unroll
                for (int s = 0; s < 16; ++s) {
                    const int q = 15 - s;
                    const half8_t v = tile[q * PPITCH + pslot];
                    const float hu = dpp_prev(h1);
                    const float hd = dpp_next(h0);
                    const float n0 = fmaf((float)v[1], hu,
                                     fmaf((float)v[2], h0,
                                     fmaf((float)v[3], h1, (float)v[0])));
                    const float n1 = fmaf((float)v[5], h0,
                                     fmaf((float)v[6], h1,
                                     fmaf((float)v[7], hd, (float)v[4])));
                    h0 = n0; h1 = n1;
                    hv0[q] = h0; hv1[q] = h1;
                }
                if (owned) hl0[pslot] = make_float2(h0, h1);
            }
        }
        if (owned && emit) {   // store half B
            float* b0 = Op + (size_t)r0g * WW + (size_t)w0;
            #pragma unroll
            for (int j = 0; j < 4; ++j) {
                *(float4*)(b0 + 4 * j)      = make_float4(hv0[4*j], hv0[4*j+1], hv0[4*j+2], hv0[4*j+3]);
                *(float4*)(b0 + WW + 4 * j) = make_float4(hv1[4*j], hv1[4*j+1], hv1[4*j+2], hv1[4*j+3]);
            }
        }
        lds_barrier();   // hl0 publish visible + tile rewrite safe
    }
}

extern "C" void kernel_launch(void* const* d_in, const int* in_sizes, int n_in,
                              void* d_out, int out_size, void* d_ws, size_t ws_size,
                              hipStream_t stream) {
    const float* X  = (const float*)d_in[0];
    const float* G1 = (const float*)d_in[1];
    const float* G2 = (const float*)d_in[2];
    const float* G3 = (const float*)d_in[3];
    float* OUT = (float*)d_out;

    const int nblocks = 4 * 32 * 2;   // 128 slices x 2 W-chunks = 256 = #CUs
    const size_t smem = (size_t)32 * PPITCH * 16 + 2 * NPAIR * sizeof(float2);

    (void)hipFuncSetAttribute((const void*)spn_kernel,
                              hipFuncAttributeMaxDynamicSharedMemorySize, (int)smem);

    spn_kernel<<<nblocks, NT, smem, stream>>>(X, G1, G2, G3, OUT);
}

// Round 13
// 154.119 us; speedup vs baseline: 1.2893x; 1.2893x over previous
//
#include <hip/hip_runtime.h>

// Gated SPN, reverse scan over W:
//   h(i,t) = a*x + g1*h(i-1,t+1) + g2*h(i,t+1) + g3*h(i+1,t+1), a = 1-g1-g2-g3
//
// r13: 512 blocks = 128 slices x 2 W-chunks x 2 H-halves -> 2 blocks/CU.
// Memory/compute overlap comes from BLOCK concurrency (one block's scan
// overlaps the other's loads) -- rounds 8-12 proved the compiler never holds
// a register prefetch across the scan. 128B-granule loads kept (r7's win).
// H-split needs NO sync: each H-half computes 12 extra halo rows; boundary
// error (injected where the un-computed neighbor row is treated as 0) decays
// ~3x per row of inward propagation (normalized gates, mean |g|~1/3), so
// output error ~3^-12 ~ 2e-6. Same non-expansiveness argument as W-warmup.
// Per block: 268 computed rows, 6 waves x 48-owned-row cones with 8-row DPP
// halos re-anchored every 8 steps (parity-double-buffered h-lines).
// WT=32 fp16-packed tile (78.6KB LDS) -> exactly 2 blocks/CU.

#define HH 512
#define WW 512
#define WT 32
#define NT 384             // 6 waves
#define PITCH 305          // tile row-slot pitch (slots 0..304)
#define HLN 304            // h-line entries
#define NROW 268           // computed real rows per block (256 out + 12 halo)

typedef _Float16 half4_t __attribute__((ext_vector_type(4)));

__device__ __forceinline__ float dpp_prev(float v) {   // lane i <- lane i-1
    return __int_as_float(__builtin_amdgcn_update_dpp(
        0, __float_as_int(v), 0x138, 0xf, 0xf, false)); // wave_shr:1, edge->0
}
__device__ __forceinline__ float dpp_next(float v) {   // lane i <- lane i+1
    return __int_as_float(__builtin_amdgcn_update_dpp(
        0, __float_as_int(v), 0x130, 0xf, 0xf, false)); // wave_shl:1, edge->0
}

// LDS-only barrier: drains lgkm (ds_write visibility), leaves vmem in flight.
__device__ __forceinline__ void lds_barrier() {
    asm volatile("s_waitcnt lgkmcnt(0)" ::: "memory");
    __builtin_amdgcn_s_barrier();
    __builtin_amdgcn_sched_barrier(0);
}

__device__ __forceinline__ half4_t norm_pack(float xx, float g1, float g2, float g3) {
    const float sa = fabsf(g1) + fabsf(g2) + fabsf(g3);
    const float sc = (sa >= 1.0f) ? (1.0f / sa) : 1.0f;
    const float n1 = g1 * sc, n2 = g2 * sc, n3 = g3 * sc;
    const float a  = 1.0f - n1 - n2 - n3;
    half4_t v;
    v.x = (_Float16)(a * xx);
    v.y = (_Float16)n1;
    v.z = (_Float16)n2;
    v.w = (_Float16)n3;
    return v;
}

__global__ __launch_bounds__(NT, 3) void spn_kernel(
    const float* __restrict__ X, const float* __restrict__ G1,
    const float* __restrict__ G2, const float* __restrict__ G3,
    float* __restrict__ OUT)
{
    extern __shared__ char smem[];
    half4_t* tile = (half4_t*)smem;                            // [32][PITCH]
    float*   hlA  = (float*)(smem + (size_t)32 * PITCH * 8);   // [HLN] x2 (parity)
    float*   hlB  = hlA + HLN;

    const int tid = threadIdx.x;
    const int wv  = tid >> 6;
    const int L   = tid & 63;
    const int cr  = 48 * wv + L - 8;   // computed-row coord, -8 .. 295
    const int slot = cr + 8;           // 0 .. 303
    const bool owned = (L >= 8) && (L < 56);

    const int slice = blockIdx.x >> 2;
    const int wch   = blockIdx.x & 1;          // W-chunk
    const int hch   = (blockIdx.x >> 1) & 1;   // H-half
    const int cend   = wch ? WW : 288;         // scan region right edge
    const int ntiles = wch ? 8 : 9;
    const int warm   = wch ? 0 : 1;            // W-chunk A: first tile = warmup
    const int hb     = hch ? (HH - NROW) : 0;  // 0 or 244
    const int out_lo = hch ? 256 : 0;
    const int out_hi = hch ? 512 : 256;
    const int crg    = hb + cr;                // global row of this lane
    const bool do_store = owned && (crg >= out_lo) && (crg < out_hi);

    const size_t base = (size_t)slice * (size_t)(HH * WW);
    const float* Xp  = X  + base;
    const float* G1p = G1 + base;
    const float* G2p = G2 + base;
    const float* G3p = G3 + base;
    float* Op = OUT + base;

    // one-time zero-fill: tile edge slots (0..7 and 276..304, all 32 w) and
    // both h-lines. Visible at the first post-stage barrier.
    {
        half4_t z; z.x = (_Float16)0; z.y = (_Float16)0; z.z = (_Float16)0; z.w = (_Float16)0;
        for (int i = tid; i < 32 * 37; i += NT) {
            const int w = i / 37, k = i % 37;
            const int s = (k < 8) ? k : (268 + k);   // 0..7, 276..304
            tile[w * PITCH + s] = z;
        }
        for (int i = tid; i < 2 * HLN; i += NT) hlA[i] = 0.0f;
    }

    const int lq = tid & 7;    // 16B eighth of a row's 128B segment
    const int lr = tid >> 3;   // staging row within a 48-row round

    for (int t = 0; t < ntiles; ++t) {
        const int w0 = cend - WT * (t + 1);
        const bool emit = (t >= warm);

        // ---- stage tile t: 268 rows x 128B x 4 arrays, fp16-packed ----
        #pragma unroll
        for (int j = 0; j < 6; ++j) {
            const int ri = 48 * j + lr;
            if (j < 5 || ri < NROW) {
                const size_t off = (size_t)(hb + ri) * WW + (size_t)(w0 + 4 * lq);
                const float4 x  = *(const float4*)(Xp  + off);
                const float4 a1 = *(const float4*)(G1p + off);
                const float4 a2 = *(const float4*)(G2p + off);
                const float4 a3 = *(const float4*)(G3p + off);
                const int s = ri + 8;
                tile[(4 * lq + 0) * PITCH + s] = norm_pack(x.x, a1.x, a2.x, a3.x);
                tile[(4 * lq + 1) * PITCH + s] = norm_pack(x.y, a1.y, a2.y, a3.y);
                tile[(4 * lq + 2) * PITCH + s] = norm_pack(x.z, a1.z, a2.z, a3.z);
                tile[(4 * lq + 3) * PITCH + s] = norm_pack(x.w, a1.w, a2.w, a3.w);
            }
        }
        lds_barrier();   // tile visible; vmem not drained

        // ---- scan: 4 sub-phases of 8 barrier-free steps each ----
        float hv[32];
        #pragma unroll
        for (int sub = 0; sub < 4; ++sub) {
            const float* rd = (sub & 1) ? hlB : hlA;
            float*       wr = (sub & 1) ? hlA : hlB;
            float h = rd[slot];    // anchor published at end of previous sub
            #pragma unroll
            for (int s = 0; s < 8; ++s) {
                const int q = 31 - 8 * sub - s;
                const half4_t v = tile[q * PITCH + slot];
                const float hu = dpp_prev(h);
                const float hd = dpp_next(h);
                h = fmaf((float)v.y, hu,
                    fmaf((float)v.z, h,
                    fmaf((float)v.w, hd, (float)v.x)));
                hv[q] = h;
            }
            if (owned) wr[slot] = h;
            lds_barrier();
        }
        // sub3 wrote hlA -> next tile's sub0 reads hlA (parity closes)

        // ---- 128B contiguous output stores ----
        if (do_store && emit) {
            float* bo = Op + (size_t)crg * WW + (size_t)w0;
            #pragma unroll
            for (int j = 0; j < 8; ++j)
                *(float4*)(bo + 4 * j) = make_float4(hv[4 * j + 0], hv[4 * j + 1],
                                                     hv[4 * j + 2], hv[4 * j + 3]);
        }
    }
}

extern "C" void kernel_launch(void* const* d_in, const int* in_sizes, int n_in,
                              void* d_out, int out_size, void* d_ws, size_t ws_size,
                              hipStream_t stream) {
    const float* X  = (const float*)d_in[0];
    const float* G1 = (const float*)d_in[1];
    const float* G2 = (const float*)d_in[2];
    const float* G3 = (const float*)d_in[3];
    float* OUT = (float*)d_out;

    const int nblocks = 4 * 32 * 4;   // 128 slices x 2 W-chunks x 2 H-halves
    const size_t smem = (size_t)32 * PITCH * 8 + 2 * HLN * sizeof(float); // 80512B

    (void)hipFuncSetAttribute((const void*)spn_kernel,
                              hipFuncAttributeMaxDynamicSharedMemorySize, (int)smem);

    spn_kernel<<<nblocks, NT, smem, stream>>>(X, G1, G2, G3, OUT);
}